// Round 1
// baseline (746.690 us; speedup 1.0000x reference)
//
#include <hip/hip_runtime.h>
#include <math.h>

#define NQ 12
#define DIM 4096
#define NL 6
#define TPB 256

// ---- GF(2) linear algebra for the CNOT blocks -----------------------------
// Per-layer CNOT block maps labels: final[x] = initial[h(x)], h = suffix-XOR
// scan (gray-to-binary). Verified on small cases. Instead of permuting LDS,
// we relabel: after l blocks, storage map psi_l = h^l. A gate on logical bit
// p pairs slots {s, s ^ D} with D = h^l(e_p) (bit p is D's msb since h is
// lower-triangular), and the "logical 0" side is parity(s & M) == 0 with M =
// row p of gray^l.
constexpr unsigned hmap(unsigned x){ x^=x>>1; x^=x>>2; x^=x>>4; x^=x>>8; return x&0xFFFu; }
constexpr unsigned hpow(int l, unsigned x){ unsigned v=x; for(int i=0;i<l;++i) v=hmap(v); return v; }
constexpr unsigned gmap(unsigned x){ return (x^(x>>1))&0xFFFu; }
constexpr unsigned gpow(int l, unsigned x){ unsigned v=x; for(int i=0;i<l;++i) v=gmap(v); return v; }
constexpr unsigned Dent(int l, int p){ return hpow(l, 1u<<p); }
constexpr unsigned Ment(int l, int p){
  unsigned m=0;
  for(int b=0;b<NQ;++b) if((gpow(l,1u<<b)>>p)&1u) m|=1u<<b;
  return m;
}
#define DROW(l) { Dent(l,0),Dent(l,1),Dent(l,2),Dent(l,3),Dent(l,4),Dent(l,5),Dent(l,6),Dent(l,7),Dent(l,8),Dent(l,9),Dent(l,10),Dent(l,11) }
#define MROW(l) { Ment(l,0),Ment(l,1),Ment(l,2),Ment(l,3),Ment(l,4),Ment(l,5),Ment(l,6),Ment(l,7),Ment(l,8),Ment(l,9),Ment(l,10),Ment(l,11) }
__device__ constexpr unsigned DTAB[NL][NQ] = { DROW(0),DROW(1),DROW(2),DROW(3),DROW(4),DROW(5) };
__device__ constexpr unsigned MTAB[NL][NQ] = { MROW(0),MROW(1),MROW(2),MROW(3),MROW(4),MROW(5) };

// Apply 2x2 complex gate to stored pair (a at s0, b at s1). If f==1 the
// logical roles are swapped -> swap coefficients instead of data.
__device__ __forceinline__ void pair_update(float2& a, float2& b,
                                            float2 g0, float2 g1, float2 g2, float2 g3,
                                            unsigned f) {
  float2 c0 = f ? g3 : g0;
  float2 c1 = f ? g2 : g1;
  float2 c2 = f ? g1 : g2;
  float2 c3 = f ? g0 : g3;
  float nax = c0.x*a.x - c0.y*a.y + c1.x*b.x - c1.y*b.y;
  float nay = c0.x*a.y + c0.y*a.x + c1.x*b.y + c1.y*b.x;
  float nbx = c2.x*a.x - c2.y*a.y + c3.x*b.x - c3.y*b.y;
  float nby = c2.x*a.y + c2.y*a.x + c3.x*b.y + c3.y*b.x;
  a = make_float2(nax, nay);
  b = make_float2(nbx, nby);
}

// Gates on logical bits 0..3: D is confined to the low nibble (h is
// lower-triangular), so pairs stay inside each thread's 16 amplitudes.
__device__ __forceinline__ void local_gates(float2 v[16], const float2* gm,
                                            const unsigned* Dl, const unsigned* Ml,
                                            int l, int tid) {
  #pragma unroll
  for (int p = 0; p < 4; ++p) {
    const int q = NQ - 1 - p;
    const unsigned D = Dl[p], M = Ml[p];
    const float2* g = &gm[(l*NQ + q)*4];
    float2 g0 = g[0], g1 = g[1], g2 = g[2], g3 = g[3];
    unsigned pb = (unsigned)__popc((tid << 4) & (int)M) & 1u;
    #pragma unroll
    for (int k = 0; k < 16; ++k) {
      if (k & (1 << p)) continue;
      int k1 = k ^ (int)D;  // D < 16 for p<4
      unsigned f = (pb + (unsigned)__popc(k & (int)M)) & 1u;
      pair_update(v[k], v[k1], g0, g1, g2, g3, f);
    }
  }
}

// b128 LDS I/O of a thread's 16 contiguous amplitudes; chunk order rotated by
// tid so lanes spread across all 32 banks (thread-contiguous layout would
// otherwise put every lane on the same 4 banks).
__device__ __forceinline__ void load_local(float2 v[16], const float2* st, int tid) {
  const float4* st4 = (const float4*)st;
  #pragma unroll
  for (int c = 0; c < 8; ++c) {
    int cc = (c + tid) & 7;
    float4 t = st4[tid*8 + cc];
    v[2*cc]   = make_float2(t.x, t.y);
    v[2*cc+1] = make_float2(t.z, t.w);
  }
}
__device__ __forceinline__ void store_local(const float2 v[16], float2* st, int tid) {
  float4* st4 = (float4*)st;
  #pragma unroll
  for (int c = 0; c < 8; ++c) {
    int cc = (c + tid) & 7;
    st4[tid*8 + cc] = make_float4(v[2*cc].x, v[2*cc].y, v[2*cc+1].x, v[2*cc+1].y);
  }
}

// One strided gate pass for logical bit p (4..11): 2048 pairs, 8 per thread,
// lane-contiguous j -> conflict-free-ish LDS addressing.
__device__ __forceinline__ void general_pass(float2* st, const float2* gm,
                                             int l, int p, int tid) {
  const int q = NQ - 1 - p;
  const unsigned D = DTAB[l][p], M = MTAB[l][p];
  const float2* g = &gm[(l*NQ + q)*4];
  float2 g0 = g[0], g1 = g[1], g2 = g[2], g3 = g[3];
  const int lowmask = (1 << p) - 1;
  #pragma unroll
  for (int m = 0; m < 8; ++m) {
    int j = (m << 8) | tid;
    int s0 = ((j & ~lowmask) << 1) | (j & lowmask);  // insert 0 at bit p
    int s1 = s0 ^ (int)D;                            // partner (bit p set)
    unsigned f = (unsigned)__popc(s0 & (int)M) & 1u;
    float2 a = st[s0], bb = st[s1];
    pair_update(a, bb, g0, g1, g2, g3, f);
    st[s0] = a; st[s1] = bb;
  }
}

__global__ __launch_bounds__(TPB, 4)
void qsim12_kernel(const float* __restrict__ x, const float* __restrict__ w,
                   float* __restrict__ out) {
  __shared__ __align__(16) float2 st[DIM];   // 32 KB state
  __shared__ float2 gm[NL*NQ*4];             // Rot matrices, 2.25 KB
  __shared__ float2 cs[NQ];                  // cos/sin(x/2)
  __shared__ float red[4];

  const int tid = threadIdx.x;
  const int b = blockIdx.x;

  // Rot(phi,theta,omega) = RZ(om) RY(th) RZ(phi):
  //   m00 = ct e^{-i(phi+om)/2}, m01 = -st e^{+i(phi-om)/2}
  //   m10 = st e^{-i(phi-om)/2}, m11 = ct e^{+i(phi+om)/2}
  if (tid < NL*NQ) {
    const float* wp = w + tid*3;
    float phi = wp[0], th = wp[1], om = wp[2];
    float sth, cth; sincosf(0.5f*th, &sth, &cth);
    float sa, ca;   sincosf(0.5f*(phi+om), &sa, &ca);
    float sb, cb;   sincosf(0.5f*(phi-om), &sb, &cb);
    float2* g = &gm[tid*4];
    g[0] = make_float2( cth*ca, -cth*sa);
    g[1] = make_float2(-sth*cb, -sth*sb);
    g[2] = make_float2( sth*cb, -sth*sb);
    g[3] = make_float2( cth*ca,  cth*sa);
  }
  if (tid >= 128 && tid < 128 + NQ) {
    int q = tid - 128;
    float xv = x[b*NQ + q];
    float sv, cv; sincosf(0.5f*xv, &sv, &cv);
    cs[q] = make_float2(cv, sv);
  }
  __syncthreads();

  // Init: |0..0> through RX encoding is a tensor product:
  // amp(idx) = prod_p (bit_p ? sin : cos) * (-i)^popcount(idx). Fold layer-0's
  // local gates (bits 0..3) in before the first store.
  {
    float2 v[16];
    float rhi = 1.f; int pophi = 0;
    #pragma unroll
    for (int pb = 0; pb < 8; ++pb) {           // slot bits 4..11, qubit 7-pb
      int bit = (tid >> pb) & 1;
      float2 c = cs[7 - pb];
      rhi *= bit ? c.y : c.x;
      pophi += bit;
    }
    #pragma unroll
    for (int k = 0; k < 16; ++k) {
      float r = rhi; int pop = pophi;
      #pragma unroll
      for (int p2 = 0; p2 < 4; ++p2) {         // slot bits 0..3, qubit 11-p2
        int bit = (k >> p2) & 1;
        float2 c = cs[11 - p2];
        r *= bit ? c.y : c.x;
        pop += bit;
      }
      int pm = pop & 3;
      float2 amp;
      amp.x = (pm == 0) ? r : ((pm == 2) ? -r : 0.f);
      amp.y = (pm == 1) ? -r : ((pm == 3) ? r : 0.f);
      v[k] = amp;
    }
    local_gates(v, gm, DTAB[0], MTAB[0], 0, tid);
    store_local(v, st, tid);
  }
  __syncthreads();

  for (int l = 0; l < NL; ++l) {
    if (l > 0) {
      float2 v[16];
      load_local(v, st, tid);
      local_gates(v, gm, DTAB[l], MTAB[l], l, tid);
      store_local(v, st, tid);
      __syncthreads();
    }
    #pragma unroll
    for (int p = 4; p < NQ; ++p) {
      general_pass(st, gm, l, p, tid);
      __syncthreads();
    }
    // CNOT block: pure relabeling, encoded in DTAB/MTAB for the next layer.
  }

  // Output: logical bits 11/10 of the final state equal the slot bits
  // (gray^6 only mixes downward), so signs are wave-uniform per thread chunk.
  float s = 0.f;
  {
    const float4* st4 = (const float4*)st;
    #pragma unroll
    for (int c = 0; c < 8; ++c) {
      int cc = (c + tid) & 7;
      float4 t = st4[tid*8 + cc];
      s += t.x*t.x + t.y*t.y + t.z*t.z + t.w*t.w;
    }
  }
  #pragma unroll
  for (int off = 32; off >= 1; off >>= 1) s += __shfl_down(s, off);
  if ((tid & 63) == 0) red[tid >> 6] = s;
  __syncthreads();
  if (tid == 0) {
    float S0 = red[0], S1 = red[1], S2 = red[2], S3 = red[3];
    out[b*2 + 0] = (S0 + S1) - (S2 + S3);  // sign by slot bit 11 (wave 2,3 negative)
    out[b*2 + 1] = (S0 - S1) + (S2 - S3);  // sign by slot bit 10 (odd waves negative)
  }
}

extern "C" void kernel_launch(void* const* d_in, const int* in_sizes, int n_in,
                              void* d_out, int out_size, void* d_ws, size_t ws_size,
                              hipStream_t stream) {
  const float* x = (const float*)d_in[0];      // (B, 12) f32
  const float* w = (const float*)d_in[1];      // (6, 12, 3) f32
  float* out = (float*)d_out;                  // (B, 2) f32
  int B = in_sizes[0] / NQ;
  qsim12_kernel<<<B, TPB, 0, stream>>>(x, w, out);
}

// Round 2
// 226.278 us; speedup vs baseline: 3.2999x; 3.2999x over previous
//
#include <hip/hip_runtime.h>
#include <math.h>

#define NQ 12
#define DIM 4096
#define NL 6
#define TPB 256

// ---- GF(2) relabeling for the CNOT blocks ---------------------------------
// Layer-l CNOT block = label permutation h (gray-to-binary). We never permute
// LDS; a gate on logical bit p after l blocks pairs slots {s, s^D_p} with
// D_p = h^l(e_p), and the logical-0 side has parity(s & M_p)==0 with M_p =
// row p of gray^l. Since gray^l = (h^l)^{-1}, parity(D_r & M_q) = delta_qr:
// within an XOR-coset indexed by coefficients on {D_p}, gate p's swap flag is
// uniform (= parity(rep & M_p)).
constexpr unsigned hmap(unsigned x){ x^=x>>1; x^=x>>2; x^=x>>4; x^=x>>8; return x&0xFFFu; }
constexpr unsigned gmap(unsigned x){ return (x^(x>>1))&0xFFFu; }
constexpr unsigned hpow(int l, unsigned x){ unsigned v=x; for(int i=0;i<l;++i) v=hmap(v); return v; }
constexpr unsigned gpow(int l, unsigned x){ unsigned v=x; for(int i=0;i<l;++i) v=gmap(v); return v; }
constexpr unsigned Dent(int l, int p){ return hpow(l, 1u<<p); }
constexpr unsigned Ment(int l, int p){
  unsigned m=0; for(int b=0;b<NQ;++b) if((gpow(l,1u<<b)>>p)&1u) m|=1u<<b; return m;
}

struct Tabs {
  unsigned M[NL][NQ];    // parity masks per (layer, logical bit)
  unsigned KL[NL][16];   // combos of D[l][0..3]   (< 16, stay in-chunk)
  unsigned C4[NL][16];   // combos of D[l][4..7]   (< 256)
  unsigned C8[NL][16];   // combos of D[l][8..11]
};
constexpr Tabs make_tabs() {
  Tabs t{};
  for (int l=0;l<NL;++l) {
    for (int p=0;p<NQ;++p) t.M[l][p]=Ment(l,p);
    for (int idx=0;idx<16;++idx) {
      unsigned a=0,b=0,c=0;
      for (int i=0;i<4;++i) if ((idx>>i)&1) { a^=Dent(l,i); b^=Dent(l,4+i); c^=Dent(l,8+i); }
      t.KL[l][idx]=a; t.C4[l][idx]=b; t.C8[l][idx]=c;
    }
  }
  return t;
}
__device__ constexpr Tabs TB = make_tabs();

// bank swizzle: XOR slot bits [3:1] with chunk-owner bits [6:4]
__device__ __forceinline__ int physf2(int s) { return s ^ ((s >> 3) & 0xE); }

// 2x2 complex gate on (a,b); coefficients pre-selected for the swap flag.
// a' = c0*a + c1*b ; b' = c2*a + c3*b   (complex)
__device__ __forceinline__ void cmul2(float2& a, float2& b,
                                      float2 c0, float2 c1, float2 c2, float2 c3) {
  float nax = c0.x*a.x - c0.y*a.y + c1.x*b.x - c1.y*b.y;
  float nay = c0.x*a.y + c0.y*a.x + c1.x*b.y + c1.y*b.x;
  float nbx = c2.x*a.x - c2.y*a.y + c3.x*b.x - c3.y*b.y;
  float nby = c2.x*a.y + c2.y*a.x + c3.x*b.y + c3.y*b.x;
  a = make_float2(nax, nay);
  b = make_float2(nbx, nby);
}

// Gates on logical bits 0..3; v[] in logical order (idx = coefficients on
// D[l][0..3]); swap flag uniform per thread = parity(tid*16 & M).
__device__ __forceinline__ void local_gates_rt(float2 v[16], const float2* gm, int l, int tid) {
  #pragma unroll
  for (int p = 0; p < 4; ++p) {
    const unsigned M = TB.M[l][p];
    const float2* g = &gm[(l*NQ + (NQ-1-p))*4];
    float2 g0=g[0], g1=g[1], g2=g[2], g3=g[3];
    unsigned f = (unsigned)__popc((tid<<4) & (int)M) & 1u;
    float2 c0 = f ? g3 : g0;
    float2 c1 = f ? g2 : g1;
    float2 c2 = f ? g1 : g2;
    float2 c3 = f ? g0 : g3;
    #pragma unroll
    for (int idx = 0; idx < 16; ++idx) {
      if (idx & (1<<p)) continue;
      cmul2(v[idx], v[idx^(1<<p)], c0, c1, c2, c3);
    }
  }
}

// Gates on logical bits p0..p0+3 over a coset rep s0; v[] indexed by combo.
__device__ __forceinline__ void fused_gates(float2 v[16], const float2* gm, int l, int p0, int s0) {
  #pragma unroll
  for (int i = 0; i < 4; ++i) {
    const int p = p0 + i;
    const unsigned M = TB.M[l][p];
    const float2* g = &gm[(l*NQ + (NQ-1-p))*4];
    float2 g0=g[0], g1=g[1], g2=g[2], g3=g[3];
    unsigned f = (unsigned)__popc(s0 & (int)M) & 1u;
    float2 c0 = f ? g3 : g0;
    float2 c1 = f ? g2 : g1;
    float2 c2 = f ? g1 : g2;
    float2 c3 = f ? g0 : g3;
    #pragma unroll
    for (int idx = 0; idx < 16; ++idx) {
      if (idx & (1<<i)) continue;
      cmul2(v[idx], v[idx^(1<<i)], c0, c1, c2, c3);
    }
  }
}

__global__ __launch_bounds__(TPB, 4)
void qsim12_kernel(const float* __restrict__ x, const float* __restrict__ w,
                   float* __restrict__ out) {
  __shared__ __align__(16) float2 st[DIM];   // 32 KB state
  __shared__ float2 gm[NL*NQ*4];             // Rot matrices
  __shared__ float2 cs[NQ];                  // cos/sin(x/2)
  __shared__ float red[8];

  const int tid = threadIdx.x;
  const int b = blockIdx.x;
  const int xr = (tid & 7) << 1;             // local-chunk swizzle

  // Rot(phi,theta,omega) = RZ(om) RY(th) RZ(phi)
  if (tid < NL*NQ) {
    const float* wp = w + tid*3;
    float phi = wp[0], th = wp[1], om = wp[2];
    float sth, cth; sincosf(0.5f*th, &sth, &cth);
    float sa, ca;   sincosf(0.5f*(phi+om), &sa, &ca);
    float sb, cb;   sincosf(0.5f*(phi-om), &sb, &cb);
    float2* g = &gm[tid*4];
    g[0] = make_float2( cth*ca, -cth*sa);
    g[1] = make_float2(-sth*cb, -sth*sb);
    g[2] = make_float2( sth*cb, -sth*sb);
    g[3] = make_float2( cth*ca,  cth*sa);
  }
  if (tid >= 128 && tid < 128 + NQ) {
    int q = tid - 128;
    float xv = x[b*NQ + q];
    float sv, cv; sincosf(0.5f*xv, &sv, &cv);
    cs[q] = make_float2(cv, sv);
  }
  __syncthreads();

  float2 v[16];

  // Init: amp(slot) = prod_w (bit_w ? sin_w : cos_w) * (-i)^popcount.
  // At l=0 logical == physical (KL[0][idx] = idx), so fill v in index order
  // and fold layer 0's local gates before the first store.
  {
    float rhi = 1.f; int pophi = 0;
    #pragma unroll
    for (int pb = 0; pb < 8; ++pb) {           // slot bits 4..11 -> wire 7-pb
      int bit = (tid >> pb) & 1;
      float2 c = cs[7 - pb];
      rhi *= bit ? c.y : c.x;
      pophi += bit;
    }
    #pragma unroll
    for (int k = 0; k < 16; ++k) {
      float r = rhi; int pop = pophi;
      #pragma unroll
      for (int p2 = 0; p2 < 4; ++p2) {         // slot bits 0..3 -> wire 11-p2
        int bit = (k >> p2) & 1;
        float2 c = cs[11 - p2];
        r *= bit ? c.y : c.x;
        pop += bit;
      }
      int pm = pop & 3;
      float2 amp;
      amp.x = (pm == 0) ? r : ((pm == 2) ? -r : 0.f);
      amp.y = (pm == 1) ? -r : ((pm == 3) ? r : 0.f);
      v[k] = amp;
    }
  }
  local_gates_rt(v, gm, 0, tid);
  #pragma unroll
  for (int idx = 0; idx < 16; ++idx)
    st[tid*16 + (int)(TB.KL[0][idx] ^ (unsigned)xr)] = v[idx];
  __syncthreads();

  const int s0a = (tid & 15) | ((tid & ~15) << 4);  // rep for bits-4..7 coset
  // PA=1 rep: tid itself (tid < 256, bits 8..11 zeroed trivially)

  for (int l = 0; l < NL; ++l) {
    // fused pass A: logical bits 4..7
    #pragma unroll
    for (int idx = 0; idx < 16; ++idx) {
      int s = s0a ^ (int)TB.C4[l][idx];
      v[idx] = st[physf2(s)];
    }
    fused_gates(v, gm, l, 4, s0a);
    #pragma unroll
    for (int idx = 0; idx < 16; ++idx) {
      int s = s0a ^ (int)TB.C4[l][idx];
      st[physf2(s)] = v[idx];
    }
    __syncthreads();

    // fused pass B: logical bits 8..11
    #pragma unroll
    for (int idx = 0; idx < 16; ++idx) {
      int s = tid ^ (int)TB.C8[l][idx];
      v[idx] = st[physf2(s)];
    }
    fused_gates(v, gm, l, 8, tid);

    if (l < NL-1) {
      #pragma unroll
      for (int idx = 0; idx < 16; ++idx) {
        int s = tid ^ (int)TB.C8[l][idx];
        st[physf2(s)] = v[idx];
      }
      __syncthreads();
      // local pass for layer l+1 (logical bits 0..3)
      #pragma unroll
      for (int idx = 0; idx < 16; ++idx)
        v[idx] = st[tid*16 + (int)(TB.KL[l+1][idx] ^ (unsigned)xr)];
      local_gates_rt(v, gm, l+1, tid);
      #pragma unroll
      for (int idx = 0; idx < 16; ++idx)
        st[tid*16 + (int)(TB.KL[l+1][idx] ^ (unsigned)xr)] = v[idx];
      __syncthreads();
    }
  }

  // Epilogue in registers: after the last fused-B pass, element idx sits at
  // slot tid ^ C8[5][idx]; slot bits 11/10 (== logical bits 11/10, since
  // gray^6's rows 11,10 are e11,e10) come from the compile-time coset offset.
  float a0 = 0.f, a1 = 0.f;
  #pragma unroll
  for (int idx = 0; idx < 16; ++idx) {
    const unsigned c = TB.C8[NL-1][idx];
    float pr = v[idx].x*v[idx].x + v[idx].y*v[idx].y;
    a0 += ((c >> 11) & 1u) ? -pr : pr;
    a1 += ((c >> 10) & 1u) ? -pr : pr;
  }
  #pragma unroll
  for (int off = 32; off >= 1; off >>= 1) {
    a0 += __shfl_down(a0, off);
    a1 += __shfl_down(a1, off);
  }
  if ((tid & 63) == 0) { red[(tid>>6)*2] = a0; red[(tid>>6)*2+1] = a1; }
  __syncthreads();
  if (tid == 0) {
    out[b*2 + 0] = red[0] + red[2] + red[4] + red[6];
    out[b*2 + 1] = red[1] + red[3] + red[5] + red[7];
  }
}

extern "C" void kernel_launch(void* const* d_in, const int* in_sizes, int n_in,
                              void* d_out, int out_size, void* d_ws, size_t ws_size,
                              hipStream_t stream) {
  const float* x = (const float*)d_in[0];      // (B, 12) f32
  const float* w = (const float*)d_in[1];      // (6, 12, 3) f32
  float* out = (float*)d_out;                  // (B, 2) f32
  int B = in_sizes[0] / NQ;
  qsim12_kernel<<<B, TPB, 0, stream>>>(x, w, out);
}